// Round 5
// baseline (547.851 us; speedup 1.0000x reference)
//
#include <hip/hip_runtime.h>
#include <hip/hip_bf16.h>

#define HID   51
#define MR    208          // 204 gate rows + y row (204) padded to 13 tiles of 16
#define SEQT  999
#define EPB   16           // batch elements per block -> 256 blocks, full-width lanes
#define NTH   448          // 7 waves: waves 0-5 = 2 tiles each, wave 6 = tile 12 + service
#define BSTR  72           // bcol row stride in halves (144 B: 16B-aligned, free 2-way)

typedef __attribute__((ext_vector_type(8))) short  short8;   // 8 bf16 = 4 VGPRs
typedef __attribute__((ext_vector_type(4))) float  floatx4;
typedef __attribute__((ext_vector_type(2))) float  floatx2;  // -> v_pk_*_f32

// A_ext[208][64] bf16, PRE-SCALED by -log2(e) (i,f,o) or -2*log2(e) (g).
// Row->unit map is PERMUTED so wave w's two tiles (2w, 2w+1) give lane group
// g4 the ADJACENT units 8w+2*g4 and 8w+2*g4+1 (packed dword h-write):
//   tile T<12, row group g4r, gate: unit u = 8*(T>>1) + 2*g4r + (T&1)
//   tile 12: g4r<3 -> unit 48+g4r;  g4r==3,gate==0 -> y row (W_fc, UNSCALED)
__global__ void prep_kernel(const float* __restrict__ W_hh,
                            const float* __restrict__ W_ih,
                            const float* __restrict__ W_fc,
                            __hip_bfloat16* __restrict__ A_ext)
{
    const float K1 = 1.442695040889f;
    int idx = blockIdx.x * blockDim.x + threadIdx.x;
    if (idx >= MR * 64) return;
    int r = idx >> 6, k = idx & 63;
    int T = r >> 4, r16 = r & 15, g4r = r16 >> 2, gate = r16 & 3;
    float v = 0.f;
    if (T < 12) {
        int u = ((T >> 1) << 3) + 2 * g4r + (T & 1);
        float s = (gate == 2) ? (-2.f * K1) : (-K1);
        if (k < HID)      v = s * W_hh[(gate * HID + u) * HID + k];
        else if (k == 51) v = s * W_ih[gate * HID + u];
    } else {                       // tile 12
        if (g4r < 3) {
            int u = 48 + g4r;
            float s = (gate == 2) ? (-2.f * K1) : (-K1);
            if (k < HID)      v = s * W_hh[(gate * HID + u) * HID + k];
            else if (k == 51) v = s * W_ih[gate * HID + u];
        } else if (gate == 0) {    // row 204: y row
            if (k < HID) v = W_fc[k];
        }
    }
    A_ext[idx] = __float2bfloat16(v);
}

__launch_bounds__(NTH)
__global__ void lstm_mfma_kernel(const float* __restrict__ x,
                                 const float* __restrict__ b_ih,
                                 const float* __restrict__ b_hh,
                                 const float* __restrict__ b_fc,
                                 const __hip_bfloat16* __restrict__ A_ext,
                                 float* __restrict__ out)
{
    // ONLY LDS: the double-buffered h/x column block (4.6 KB)
    __shared__ __hip_bfloat16 bcol[2][16 * BSTR];

    const int tid  = threadIdx.x;
    const int w    = tid >> 6;    // 0..5 double-tile waves, 6 = tile-12 + service
    const int lane = tid & 63;
    const int e    = lane & 15;   // MFMA col — all 16 live
    const int g4   = lane >> 4;   // lane group
    const int e0   = blockIdx.x * EPB;
    const bool w6  = (w == 6);
    // wave 6 tile-12 units: 48+g4 for g4<3; g4==3 lanes own the y row (204)
    const int  uB6 = 48 + g4;
    const bool yln = w6 && (g4 == 3);    // y direct-store lanes
    const bool xsv = w6 && (g4 == 0);    // x feeder lanes

    const float K1  = 1.442695040889f;
    const float K2N = -2.885390081777f;      // -2*log2(e)
    const floatx4 z4 = {0.f, 0.f, 0.f, 0.f};

    // waves 0-5: tiles 2w, 2w+1 -> ADJACENT units ua=8w+2g4, ub=ua+1
    short8  A0a = {0,0,0,0,0,0,0,0}, A1a = {0,0,0,0,0,0,0,0};
    short8  A0b = {0,0,0,0,0,0,0,0}, A1b = {0,0,0,0,0,0,0,0};
    floatx4 bqa = {0.f, 0.f, 0.f, 0.f}, bqb = {0.f, 0.f, 0.f, 0.f};
    floatx2 cs2 = {0.f, 0.f};                // packed cell states (a,b)
    float   cs6 = 0.f;                       // wave-6 scalar cell state
    int ua = 0;

    if (!w6) {
        int Ta = 2 * w, Tb = 2 * w + 1;
        ua = 8 * w + 2 * g4;                 // even; ub = ua+1
        int ma = Ta * 16 + e, mb = Tb * 16 + e;
        A0a = *(const short8*)&A_ext[ma * 64 + g4 * 8];
        A1a = *(const short8*)&A_ext[ma * 64 + 32 + g4 * 8];
        A0b = *(const short8*)&A_ext[mb * 64 + g4 * 8];
        A1b = *(const short8*)&A_ext[mb * 64 + 32 + g4 * 8];
#pragma unroll
        for (int gg = 0; gg < 4; ++gg) {
            float s = (gg == 2) ? (-2.f * K1) : (-K1);
            bqa[gg] = s * (b_ih[gg * HID + ua]     + b_hh[gg * HID + ua]);
            bqb[gg] = s * (b_ih[gg * HID + ua + 1] + b_hh[gg * HID + ua + 1]);
        }
    } else {
        int m = 12 * 16 + e;
        A0a = *(const short8*)&A_ext[m * 64 + g4 * 8];
        A1a = *(const short8*)&A_ext[m * 64 + 32 + g4 * 8];
        if (uB6 < HID) {
#pragma unroll
            for (int gg = 0; gg < 4; ++gg) {
                float s = (gg == 2) ? (-2.f * K1) : (-K1);
                bqa[gg] = s * (b_ih[gg * HID + uB6] + b_hh[gg * HID + uB6]);
            }
        }
    }

    // per-lane global pointers for the service roles (used only where masked)
    const float* xp = x   + (size_t)(e0 + e) * SEQT;
    float*       yp = out + (size_t)(e0 + e) * SEQT;
    const float  bfc = b_fc[0];

    // x register rotation: xa = x[t+1] at step t, xb in flight (2 ahead)
    float xa = 0.f, xb = 0.f;
    if (xsv) { xa = xp[1]; xb = xp[2]; }

    for (int i = tid; i < 16 * BSTR; i += NTH) {
        bcol[0][i] = __float2bfloat16(0.f);
        bcol[1][i] = __float2bfloat16(0.f);
    }
    __syncthreads();   // zero-init fully ordered before x0 seed
    if (tid < EPB)
        bcol[0][tid * BSTR + 51] = __float2bfloat16(x[(size_t)(e0 + tid) * SEQT]);
    __syncthreads();

    auto STEP = [&](int t, int rp) {
        const int wp = rp ^ 1;

        short8 B0 = *(const short8*)&bcol[rp][e * BSTR + g4 * 8];
        short8 B1 = *(const short8*)&bcol[rp][e * BSTR + 32 + g4 * 8];

        if (!w6) {
            // 4 INDEPENDENT MFMAs (split accumulators)
            floatx4 aa = __builtin_amdgcn_mfma_f32_16x16x32_bf16(A0a, B0, bqa, 0, 0, 0);
            floatx4 a2 = __builtin_amdgcn_mfma_f32_16x16x32_bf16(A1a, B1, z4,  0, 0, 0);
            floatx4 ab = __builtin_amdgcn_mfma_f32_16x16x32_bf16(A0b, B0, bqb, 0, 0, 0);
            floatx4 b2 = __builtin_amdgcn_mfma_f32_16x16x32_bf16(A1b, B1, z4,  0, 0, 0);

            floatx4 sa = aa + a2;        // v_pk_add_f32
            floatx4 sb = ab + b2;

            float EiA = __builtin_amdgcn_exp2f(sa[0]);
            float EiB = __builtin_amdgcn_exp2f(sb[0]);
            float EfA = __builtin_amdgcn_exp2f(sa[1]);
            float EfB = __builtin_amdgcn_exp2f(sb[1]);
            float EgA = __builtin_amdgcn_exp2f(sa[2]);
            float EgB = __builtin_amdgcn_exp2f(sb[2]);
            float EoA = __builtin_amdgcn_exp2f(sa[3]);
            float EoB = __builtin_amdgcn_exp2f(sb[3]);

            floatx2 Ei2 = {EiA, EiB};
            floatx2 Ef2 = {EfA, EfB};
            floatx2 Eg2 = {EgA, EgB};
            floatx2 Eo2 = {EoA, EoB};

            // merged-denominator cell update, PACKED:
            //   P=(1+Ei)(1+Eg), F1=1+Ef,  c' = (c*P + K2N*(1-Eg)*F1)/(F1*P)
            floatx2 t2  = (Ei2 + Eg2) + 1.f;
            floatx2 P2  = __builtin_elementwise_fma(Ei2, Eg2, t2);
            floatx2 F12 = Ef2 + 1.f;
            floatx2 D2  = F12 * P2;
            floatx2 R2  = {__builtin_amdgcn_rcpf(D2[0]),
                           __builtin_amdgcn_rcpf(D2[1])};
            floatx2 T2  = (1.f - Eg2) * F12;
            cs2 = __builtin_elementwise_fma(cs2, P2, K2N * T2) * R2;

            floatx2 Ec2 = {__builtin_amdgcn_exp2f(cs2[0]),
                           __builtin_amdgcn_exp2f(cs2[1])};
            floatx2 u2  = (Eo2 + Ec2) + 1.f;
            floatx2 D3  = __builtin_elementwise_fma(Eo2, Ec2, u2);
            floatx2 Ro2 = {__builtin_amdgcn_rcpf(D3[0]),
                           __builtin_amdgcn_rcpf(D3[1])};
            floatx2 h2  = (1.f - Ec2) * Ro2;

            unsigned hpk;
            asm("v_cvt_pk_bf16_f32 %0, %1, %2" : "=v"(hpk) : "v"(h2[0]), "v"(h2[1]));
            *(unsigned*)&bcol[wp][e * BSTR + ua] = hpk;
        } else {
            floatx4 acc = __builtin_amdgcn_mfma_f32_16x16x32_bf16(A0a, B0, bqa, 0, 0, 0);
            floatx4 ac2 = __builtin_amdgcn_mfma_f32_16x16x32_bf16(A1a, B1, z4,  0, 0, 0);

            float s0 = acc[0] + ac2[0];
            float Ei = __builtin_amdgcn_exp2f(s0);
            float Ef = __builtin_amdgcn_exp2f(acc[1] + ac2[1]);
            float Eg = __builtin_amdgcn_exp2f(acc[2] + ac2[2]);
            float Eo = __builtin_amdgcn_exp2f(acc[3] + ac2[3]);
            float P  = fmaf(Ei, Eg, (Ei + Eg) + 1.f);
            float F1 = 1.f + Ef;
            float R  = __builtin_amdgcn_rcpf(F1 * P);
            cs6 = fmaf(cs6, P, K2N * ((1.f - Eg) * F1)) * R;
            float Ec  = __builtin_amdgcn_exp2f(cs6);
            float Roc = __builtin_amdgcn_rcpf(fmaf(Eo, Ec, (Eo + Ec) + 1.f));
            float h   = (1.f - Ec) * Roc;

            if (uB6 < HID)                         // g4<3: h rows 48..50
                bcol[wp][e * BSTR + uB6] = __float2bfloat16(h);
            if (yln && t > 0)                      // y[t-1] direct to HBM
                yp[t - 1] = s0 + bfc;              // fire-and-forget
            if (xsv) {                             // x feeder: row 51 <- x[t+1]
                bcol[wp][e * BSTR + 51] = __float2bfloat16(xa);
                xa = xb;
                int tn = t + 3; tn = (tn > SEQT - 1) ? (SEQT - 1) : tn;
                xb = xp[tn];                       // 2-deep in flight
            }
        }

        // LDS-only barrier: h/x writes visible; global ops stay in flight
        asm volatile("s_waitcnt lgkmcnt(0)\n\ts_barrier" ::: "memory");
    };

    for (int t = 0; t < SEQT - 1; t += 2) {
        STEP(t, 0);
        STEP(t + 1, 1);
    }
    STEP(SEQT - 1, 0);   // t = 998 (999 = odd): reads bcol[0], writes bcol[1]

    // epilogue: y[998] from one extra MFMA pass over h_998 (in bcol[1])
    if (w6) {
        short8 B0 = *(const short8*)&bcol[1][e * BSTR + g4 * 8];
        short8 B1 = *(const short8*)&bcol[1][e * BSTR + 32 + g4 * 8];
        floatx4 acc = __builtin_amdgcn_mfma_f32_16x16x32_bf16(A0a, B0, bqa, 0, 0, 0);
        acc = __builtin_amdgcn_mfma_f32_16x16x32_bf16(A1a, B1, acc, 0, 0, 0);
        if (g4 == 3)
            out[(size_t)(e0 + e) * SEQT + (SEQT - 1)] = acc[0] + bfc;
    }
}

extern "C" void kernel_launch(void* const* d_in, const int* in_sizes, int n_in,
                              void* d_out, int out_size, void* d_ws, size_t ws_size,
                              hipStream_t stream) {
    const float* x    = (const float*)d_in[0];
    const float* W_ih = (const float*)d_in[1];
    const float* W_hh = (const float*)d_in[2];
    const float* b_ih = (const float*)d_in[3];
    const float* b_hh = (const float*)d_in[4];
    const float* W_fc = (const float*)d_in[5];
    const float* b_fc = (const float*)d_in[6];
    float* out = (float*)d_out;

    __hip_bfloat16* A_ext = (__hip_bfloat16*)d_ws;   // 208*64*2 = 26.6 KB

    prep_kernel<<<(MR * 64 + 255) / 256, 256, 0, stream>>>(W_hh, W_ih, W_fc, A_ext);
    lstm_mfma_kernel<<<4096 / EPB, NTH, 0, stream>>>(x, b_ih, b_hh,
                                                     b_fc, A_ext, out);
}

// Round 6
// 450.417 us; speedup vs baseline: 1.2163x; 1.2163x over previous
//
#include <hip/hip_runtime.h>
#include <hip/hip_bf16.h>

#define HID   51
#define MR    208          // 204 gate rows + y row (204) padded to 13 tiles of 16
#define SEQT  999
#define CH    111          // 999 = 9 * 111
#define NCH   9
#define EPB   16           // batch elements per block -> 256 blocks, full-width lanes
#define XST   17           // x/y LDS stride (EPB+1)
#define NTH   512          // 8 waves: SIMD tile-load (3,4,3,3) + service on w7
#define BSTR  72           // bcol row stride in halves (144 B: 16B-aligned, free 2-way)

typedef __attribute__((ext_vector_type(8))) short  short8;   // 8 bf16 = 4 VGPRs
typedef __attribute__((ext_vector_type(4))) float  floatx4;
typedef __attribute__((ext_vector_type(2))) float  floatx2;  // -> v_pk_*_f32

// A_ext[208][64] bf16, PRE-SCALED by -log2(e) (i,f,o) or -2*log2(e) (g).
// Row->unit map PERMUTED so a dual wave's tiles (2k,2k+1) give lane group g4
// ADJACENT units 8k+2*g4 and 8k+2*g4+1 (packed dword h-write):
//   tile T<12, row group g4r, gate: unit u = 8*(T>>1) + 2*g4r + (T&1)
//   tile 12: g4r<3 -> unit 48+g4r;  g4r==3,gate==0 -> y row (W_fc, UNSCALED)
__global__ void prep_kernel(const float* __restrict__ W_hh,
                            const float* __restrict__ W_ih,
                            const float* __restrict__ W_fc,
                            __hip_bfloat16* __restrict__ A_ext)
{
    const float K1 = 1.442695040889f;
    int idx = blockIdx.x * blockDim.x + threadIdx.x;
    if (idx >= MR * 64) return;
    int r = idx >> 6, k = idx & 63;
    int T = r >> 4, r16 = r & 15, g4r = r16 >> 2, gate = r16 & 3;
    float v = 0.f;
    if (T < 12) {
        int u = ((T >> 1) << 3) + 2 * g4r + (T & 1);
        float s = (gate == 2) ? (-2.f * K1) : (-K1);
        if (k < HID)      v = s * W_hh[(gate * HID + u) * HID + k];
        else if (k == 51) v = s * W_ih[gate * HID + u];
    } else {                       // tile 12
        if (g4r < 3) {
            int u = 48 + g4r;
            float s = (gate == 2) ? (-2.f * K1) : (-K1);
            if (k < HID)      v = s * W_hh[(gate * HID + u) * HID + k];
            else if (k == 51) v = s * W_ih[gate * HID + u];
        } else if (gate == 0) {    // row 204: y row
            if (k < HID) v = W_fc[k];
        }
    }
    A_ext[idx] = __float2bfloat16(v);
}

__launch_bounds__(NTH)
__global__ void lstm_mfma_kernel(const float* __restrict__ x,
                                 const float* __restrict__ b_ih,
                                 const float* __restrict__ b_hh,
                                 const float* __restrict__ b_fc,
                                 const __hip_bfloat16* __restrict__ A_ext,
                                 float* __restrict__ out)
{
    __shared__ __hip_bfloat16 bcol[2][16 * BSTR];
    __shared__ float x_lds[(CH + 1) * XST];   // +1 lookahead for row-51 prewrite
    __shared__ float y_lds[CH * XST];         // slot tt holds y[t0 + tt - 1]

    const int tid  = threadIdx.x;
    const int w    = tid >> 6;    // 8 waves; SIMD s hosts waves s and s+4
    const int lane = tid & 63;
    const int e    = lane & 15;   // MFMA col — all 16 live
    const int g4   = lane >> 4;   // lane group
    const int e0   = blockIdx.x * EPB;

    // Wave roles (SIMD tile-load = 3,4,3,3):
    //   w0-w3: dual, tiles (2w,2w+1)   w5: dual, tiles (8,9)
    //   w4: single, tile 10            w6: single, tile 11
    //   w7: tile 12 + service (y row, x feeder)
    const bool dual = (w < 4) || (w == 5);
    const bool w7   = (w == 7);
    int Ta, ur;                        // first tile; unit/write row
    if      (w < 4)  { Ta = 2 * w; ur = 8 * w + 2 * g4; }
    else if (w == 5) { Ta = 8;     ur = 32 + 2 * g4;    }
    else if (w == 4) { Ta = 10;    ur = 40 + 2 * g4;    }
    else if (w == 6) { Ta = 11;    ur = 41 + 2 * g4;    }
    else             { Ta = 12;    ur = 48 + g4;        }   // w7
    const bool yln   = w7 && (g4 == 3);          // y row lanes
    const bool xsv   = w7 && (g4 == 0);          // x feeder lanes
    const int  wrow7 = (ur < HID) ? ur : 63;     // w7 g4==3 dumps to row 63

    const float K1  = 1.442695040889f;
    const float K2N = -2.885390081777f;          // -2*log2(e)
    const floatx4 z4 = {0.f, 0.f, 0.f, 0.f};

    short8  A0a = {0,0,0,0,0,0,0,0}, A1a = {0,0,0,0,0,0,0,0};
    short8  A0b = {0,0,0,0,0,0,0,0}, A1b = {0,0,0,0,0,0,0,0};
    floatx4 bqa = {0.f, 0.f, 0.f, 0.f}, bqb = {0.f, 0.f, 0.f, 0.f};
    floatx2 cs2 = {0.f, 0.f};                    // packed cell states (dual)
    float   cs1 = 0.f;                           // scalar cell state (single/w7)

    {
        int ma = Ta * 16 + e;
        A0a = *(const short8*)&A_ext[ma * 64 + g4 * 8];
        A1a = *(const short8*)&A_ext[ma * 64 + 32 + g4 * 8];
        if (dual) {
            int mb = (Ta + 1) * 16 + e;
            A0b = *(const short8*)&A_ext[mb * 64 + g4 * 8];
            A1b = *(const short8*)&A_ext[mb * 64 + 32 + g4 * 8];
        }
    }
    if (ur < HID) {
#pragma unroll
        for (int gg = 0; gg < 4; ++gg) {
            float s = (gg == 2) ? (-2.f * K1) : (-K1);
            bqa[gg] = s * (b_ih[gg * HID + ur] + b_hh[gg * HID + ur]);
            if (dual)
                bqb[gg] = s * (b_ih[gg * HID + ur + 1] + b_hh[gg * HID + ur + 1]);
        }
    }

    for (int i = tid; i < 16 * BSTR; i += NTH) {
        bcol[0][i] = __float2bfloat16(0.f);
        bcol[1][i] = __float2bfloat16(0.f);
    }
    __syncthreads();   // zero-init fully ordered before x0 seed
    if (tid < EPB)
        bcol[0][tid * BSTR + 51] = __float2bfloat16(x[(size_t)(e0 + tid) * SEQT]);
    // prologue x-stage for chunk 0 (t = tt, always < SEQT)
    for (int i2 = tid; i2 < (CH + 1) * EPB; i2 += NTH) {
        int ee = i2 / (CH + 1), tt = i2 % (CH + 1);
        x_lds[tt * XST + ee] = x[(size_t)(e0 + ee) * SEQT + tt];
    }
    const float bfc = b_fc[0];

    __syncthreads();

    for (int tc = 0; tc < NCH; ++tc) {
        const int t0 = tc * CH;

        // prefetch next chunk's x into registers (hides HBM latency under steps)
        float xpre[4];
        {
            const int t0n = t0 + CH;
#pragma unroll
            for (int q = 0; q < 4; ++q) {
                int i2 = tid + q * NTH;
                xpre[q] = 0.f;
                if (i2 < (CH + 1) * EPB) {
                    int ee = i2 / (CH + 1), tt = i2 - ee * (CH + 1);
                    int t = t0n + tt;
                    if (t < SEQT) xpre[q] = x[(size_t)(e0 + ee) * SEQT + t];
                }
            }
        }

        for (int tt = 0; tt < CH; ++tt) {
            const int t  = t0 + tt;
            const int rp = t & 1, wp = rp ^ 1;

            short8 B0 = *(const short8*)&bcol[rp][e * BSTR + g4 * 8];
            short8 B1 = *(const short8*)&bcol[rp][e * BSTR + 32 + g4 * 8];

            if (dual) {
                // 4 INDEPENDENT MFMAs (split accumulators)
                floatx4 aa = __builtin_amdgcn_mfma_f32_16x16x32_bf16(A0a, B0, bqa, 0, 0, 0);
                floatx4 a2 = __builtin_amdgcn_mfma_f32_16x16x32_bf16(A1a, B1, z4,  0, 0, 0);
                floatx4 ab = __builtin_amdgcn_mfma_f32_16x16x32_bf16(A0b, B0, bqb, 0, 0, 0);
                floatx4 b2 = __builtin_amdgcn_mfma_f32_16x16x32_bf16(A1b, B1, z4,  0, 0, 0);

                floatx4 sa = aa + a2;        // v_pk_add_f32
                floatx4 sb = ab + b2;

                float EiA = __builtin_amdgcn_exp2f(sa[0]);
                float EiB = __builtin_amdgcn_exp2f(sb[0]);
                float EfA = __builtin_amdgcn_exp2f(sa[1]);
                float EfB = __builtin_amdgcn_exp2f(sb[1]);
                float EgA = __builtin_amdgcn_exp2f(sa[2]);
                float EgB = __builtin_amdgcn_exp2f(sb[2]);
                float EoA = __builtin_amdgcn_exp2f(sa[3]);
                float EoB = __builtin_amdgcn_exp2f(sb[3]);

                floatx2 Ei2 = {EiA, EiB};
                floatx2 Ef2 = {EfA, EfB};
                floatx2 Eg2 = {EgA, EgB};
                floatx2 Eo2 = {EoA, EoB};

                // merged-denominator cell update, PACKED:
                //   P=(1+Ei)(1+Eg), F1=1+Ef,  c' = (c*P + K2N*(1-Eg)*F1)/(F1*P)
                floatx2 t2  = (Ei2 + Eg2) + 1.f;
                floatx2 P2  = __builtin_elementwise_fma(Ei2, Eg2, t2);
                floatx2 F12 = Ef2 + 1.f;
                floatx2 D2  = F12 * P2;
                floatx2 R2  = {__builtin_amdgcn_rcpf(D2[0]),
                               __builtin_amdgcn_rcpf(D2[1])};
                floatx2 T2  = (1.f - Eg2) * F12;
                cs2 = __builtin_elementwise_fma(cs2, P2, K2N * T2) * R2;

                floatx2 Ec2 = {__builtin_amdgcn_exp2f(cs2[0]),
                               __builtin_amdgcn_exp2f(cs2[1])};
                floatx2 u2  = (Eo2 + Ec2) + 1.f;
                floatx2 D3  = __builtin_elementwise_fma(Eo2, Ec2, u2);
                floatx2 Ro2 = {__builtin_amdgcn_rcpf(D3[0]),
                               __builtin_amdgcn_rcpf(D3[1])};
                floatx2 h2  = (1.f - Ec2) * Ro2;

                unsigned hpk;
                asm("v_cvt_pk_bf16_f32 %0, %1, %2" : "=v"(hpk) : "v"(h2[0]), "v"(h2[1]));
                *(unsigned*)&bcol[wp][e * BSTR + ur] = hpk;
            } else {
                floatx4 acc = __builtin_amdgcn_mfma_f32_16x16x32_bf16(A0a, B0, bqa, 0, 0, 0);
                floatx4 ac2 = __builtin_amdgcn_mfma_f32_16x16x32_bf16(A1a, B1, z4,  0, 0, 0);

                float s0 = acc[0] + ac2[0];
                float Ei = __builtin_amdgcn_exp2f(s0);
                float Ef = __builtin_amdgcn_exp2f(acc[1] + ac2[1]);
                float Eg = __builtin_amdgcn_exp2f(acc[2] + ac2[2]);
                float Eo = __builtin_amdgcn_exp2f(acc[3] + ac2[3]);
                float P  = fmaf(Ei, Eg, (Ei + Eg) + 1.f);
                float F1 = 1.f + Ef;
                float R  = __builtin_amdgcn_rcpf(F1 * P);
                cs1 = fmaf(cs1, P, K2N * ((1.f - Eg) * F1)) * R;
                float Ec  = __builtin_amdgcn_exp2f(cs1);
                float Roc = __builtin_amdgcn_rcpf(fmaf(Eo, Ec, (Eo + Ec) + 1.f));
                float h   = (1.f - Ec) * Roc;

                if (!w7) {                           // w4 / w6: own unit row
                    bcol[wp][e * BSTR + ur] = __float2bfloat16(h);
                } else {
                    bcol[wp][e * BSTR + wrow7] = __float2bfloat16((ur < HID) ? h : 0.f);
                    if (yln) y_lds[tt * XST + e] = s0 + bfc;   // y[t-1], free
                    if (xsv) bcol[wp][e * BSTR + 51] =
                                 __float2bfloat16(x_lds[(tt + 1) * XST + e]);
                }
            }

            // LDS-only barrier: global prefetch loads stay in flight
            asm volatile("s_waitcnt lgkmcnt(0)\n\ts_barrier" ::: "memory");
        }

        // flush y[t0-1 .. t0+CH-2] (slot tt <-> t0+tt-1); skip t = -1
        for (int i2 = tid; i2 < CH * EPB; i2 += NTH) {
            int ee = i2 / CH, tt = i2 % CH;
            int t = t0 + tt - 1;
            if (t >= 0)
                out[(size_t)(e0 + ee) * SEQT + t] = y_lds[tt * XST + ee];
        }
        // commit prefetched x for the next chunk
#pragma unroll
        for (int q = 0; q < 4; ++q) {
            int i2 = tid + q * NTH;
            if (i2 < (CH + 1) * EPB) {
                int ee = i2 / (CH + 1), tt = i2 - ee * (CH + 1);
                x_lds[tt * XST + ee] = xpre[q];
            }
        }
        __syncthreads();
    }

    // epilogue: y[998] from one extra MFMA pass over h_998 (in bcol[1])
    if (w7) {
        short8 B0 = *(const short8*)&bcol[1][e * BSTR + g4 * 8];
        short8 B1 = *(const short8*)&bcol[1][e * BSTR + 32 + g4 * 8];
        floatx4 acc = __builtin_amdgcn_mfma_f32_16x16x32_bf16(A0a, B0, bqa, 0, 0, 0);
        acc = __builtin_amdgcn_mfma_f32_16x16x32_bf16(A1a, B1, acc, 0, 0, 0);
        if (g4 == 3)
            out[(size_t)(e0 + e) * SEQT + (SEQT - 1)] = acc[0] + bfc;
    }
}

extern "C" void kernel_launch(void* const* d_in, const int* in_sizes, int n_in,
                              void* d_out, int out_size, void* d_ws, size_t ws_size,
                              hipStream_t stream) {
    const float* x    = (const float*)d_in[0];
    const float* W_ih = (const float*)d_in[1];
    const float* W_hh = (const float*)d_in[2];
    const float* b_ih = (const float*)d_in[3];
    const float* b_hh = (const float*)d_in[4];
    const float* W_fc = (const float*)d_in[5];
    const float* b_fc = (const float*)d_in[6];
    float* out = (float*)d_out;

    __hip_bfloat16* A_ext = (__hip_bfloat16*)d_ws;   // 208*64*2 = 26.6 KB

    prep_kernel<<<(MR * 64 + 255) / 256, 256, 0, stream>>>(W_hh, W_ih, W_fc, A_ext);
    lstm_mfma_kernel<<<4096 / EPB, NTH, 0, stream>>>(x, b_ih, b_hh,
                                                     b_fc, A_ext, out);
}

// Round 7
// 426.459 us; speedup vs baseline: 1.2847x; 1.0562x over previous
//
#include <hip/hip_runtime.h>
#include <hip/hip_bf16.h>

#define HID   51
#define MR    208          // 204 gate rows + y row (204) padded to 13 tiles of 16
#define SEQT  999
#define CH    111          // 999 = 9 * 111
#define NCH   9
#define EPB   16           // batch elements per block -> 256 blocks, full-width lanes
#define XST   17           // x/y LDS stride (EPB+1)
#define NTH   448          // 7 waves: waves 0-5 = 2 tiles each, wave 6 = tile 12 + service
#define BSTR  72           // bcol row stride in halves (144 B: 16B-aligned, free 2-way)

typedef __attribute__((ext_vector_type(8))) short  short8;   // 8 bf16 = 4 VGPRs
typedef __attribute__((ext_vector_type(4))) float  floatx4;
typedef __attribute__((ext_vector_type(2))) float  floatx2;  // -> v_pk_*_f32

// A_ext[208][64] bf16, PRE-SCALED by -log2(e) (i,f,o) or -2*log2(e) (g).
// Row->unit map is PERMUTED so wave w's two tiles (2w, 2w+1) give lane group
// g4 the ADJACENT units 8w+2*g4 and 8w+2*g4+1 (packed dword h-write):
//   tile T<12, row group g4r, gate: unit u = 8*(T>>1) + 2*g4r + (T&1)
//   tile 12: g4r<3 -> unit 48+g4r;  g4r==3,gate==0 -> y row (W_fc, UNSCALED)
__global__ void prep_kernel(const float* __restrict__ W_hh,
                            const float* __restrict__ W_ih,
                            const float* __restrict__ W_fc,
                            __hip_bfloat16* __restrict__ A_ext)
{
    const float K1 = 1.442695040889f;
    int idx = blockIdx.x * blockDim.x + threadIdx.x;
    if (idx >= MR * 64) return;
    int r = idx >> 6, k = idx & 63;
    int T = r >> 4, r16 = r & 15, g4r = r16 >> 2, gate = r16 & 3;
    float v = 0.f;
    if (T < 12) {
        int u = ((T >> 1) << 3) + 2 * g4r + (T & 1);
        float s = (gate == 2) ? (-2.f * K1) : (-K1);
        if (k < HID)      v = s * W_hh[(gate * HID + u) * HID + k];
        else if (k == 51) v = s * W_ih[gate * HID + u];
    } else {                       // tile 12
        if (g4r < 3) {
            int u = 48 + g4r;
            float s = (gate == 2) ? (-2.f * K1) : (-K1);
            if (k < HID)      v = s * W_hh[(gate * HID + u) * HID + k];
            else if (k == 51) v = s * W_ih[gate * HID + u];
        } else if (gate == 0) {    // row 204: y row
            if (k < HID) v = W_fc[k];
        }
    }
    A_ext[idx] = __float2bfloat16(v);
}

__launch_bounds__(NTH)
__global__ void lstm_mfma_kernel(const float* __restrict__ x,
                                 const float* __restrict__ b_ih,
                                 const float* __restrict__ b_hh,
                                 const float* __restrict__ b_fc,
                                 const __hip_bfloat16* __restrict__ A_ext,
                                 float* __restrict__ out)
{
    __shared__ __hip_bfloat16 bcol[2][16 * BSTR];
    __shared__ float x_lds[(CH + 1) * XST];   // +1 lookahead for row-51 prewrite
    __shared__ float y_lds[CH * XST];         // slot tt holds y[t0 + tt - 1]

    const int tid  = threadIdx.x;
    const int w    = tid >> 6;    // 0..5 double-tile waves, 6 = tile-12 + service
    const int lane = tid & 63;
    const int e    = lane & 15;   // MFMA col — all 16 live
    const int g4   = lane >> 4;   // lane group
    const int e0   = blockIdx.x * EPB;
    const bool w6  = (w == 6);
    // wave 6 tile-12 units: 48+g4 for g4<3; g4==3 lanes own the y row (204)
    const int  uB6   = 48 + g4;
    const bool yln   = w6 && (g4 == 3);
    const bool xsv   = w6 && (g4 == 0);
    const int  wrow6 = (uB6 < HID) ? uB6 : 63;   // g4==3 -> dump row 63

    const float K1  = 1.442695040889f;
    const float K2N = -2.885390081777f;      // -2*log2(e)
    const floatx4 z4 = {0.f, 0.f, 0.f, 0.f};

    // waves 0-5: tiles 2w, 2w+1 -> ADJACENT units ua=8w+2g4, ub=ua+1
    short8  A0a = {0,0,0,0,0,0,0,0}, A1a = {0,0,0,0,0,0,0,0};
    short8  A0b = {0,0,0,0,0,0,0,0}, A1b = {0,0,0,0,0,0,0,0};
    floatx4 bqa = {0.f, 0.f, 0.f, 0.f}, bqb = {0.f, 0.f, 0.f, 0.f};
    floatx2 cs2 = {0.f, 0.f};                // packed cell states (a,b)
    float   cs6 = 0.f;                       // wave-6 scalar cell state
    int ua = 0;

    if (!w6) {
        int Ta = 2 * w, Tb = 2 * w + 1;
        ua = 8 * w + 2 * g4;                 // even; ub = ua+1
        int ma = Ta * 16 + e, mb = Tb * 16 + e;
        A0a = *(const short8*)&A_ext[ma * 64 + g4 * 8];
        A1a = *(const short8*)&A_ext[ma * 64 + 32 + g4 * 8];
        A0b = *(const short8*)&A_ext[mb * 64 + g4 * 8];
        A1b = *(const short8*)&A_ext[mb * 64 + 32 + g4 * 8];
#pragma unroll
        for (int gg = 0; gg < 4; ++gg) {
            float s = (gg == 2) ? (-2.f * K1) : (-K1);
            bqa[gg] = s * (b_ih[gg * HID + ua]     + b_hh[gg * HID + ua]);
            bqb[gg] = s * (b_ih[gg * HID + ua + 1] + b_hh[gg * HID + ua + 1]);
        }
    } else {
        int m = 12 * 16 + e;
        A0a = *(const short8*)&A_ext[m * 64 + g4 * 8];
        A1a = *(const short8*)&A_ext[m * 64 + 32 + g4 * 8];
        if (uB6 < HID) {
#pragma unroll
            for (int gg = 0; gg < 4; ++gg) {
                float s = (gg == 2) ? (-2.f * K1) : (-K1);
                bqa[gg] = s * (b_ih[gg * HID + uB6] + b_hh[gg * HID + uB6]);
            }
        }
    }

    for (int i = tid; i < 16 * BSTR; i += NTH) {
        bcol[0][i] = __float2bfloat16(0.f);
        bcol[1][i] = __float2bfloat16(0.f);
    }
    __syncthreads();   // zero-init fully ordered before x0 seed
    if (tid < EPB)
        bcol[0][tid * BSTR + 51] = __float2bfloat16(x[(size_t)(e0 + tid) * SEQT]);
    // prologue x-stage for chunk 0 (t = tt, always < SEQT)
    for (int i2 = tid; i2 < (CH + 1) * EPB; i2 += NTH) {
        int ee = i2 / (CH + 1), tt = i2 % (CH + 1);
        x_lds[tt * XST + ee] = x[(size_t)(e0 + ee) * SEQT + tt];
    }
    const float bfc = b_fc[0];

    __syncthreads();

    for (int tc = 0; tc < NCH; ++tc) {
        const int t0 = tc * CH;

        // prefetch next chunk's x into registers (hides HBM latency under steps)
        float xpre[4];
        {
            const int t0n = t0 + CH;
#pragma unroll
            for (int q = 0; q < 4; ++q) {
                int i2 = tid + q * NTH;              // (CH+1)*EPB == 4*NTH exactly
                int ee = i2 / (CH + 1), tt = i2 - ee * (CH + 1);
                int t = t0n + tt;
                xpre[q] = (t < SEQT) ? x[(size_t)(e0 + ee) * SEQT + t] : 0.f;
            }
        }

        for (int tt = 0; tt < CH; ++tt) {
            const int t  = t0 + tt;
            const int rp = t & 1, wp = rp ^ 1;

            short8 B0 = *(const short8*)&bcol[rp][e * BSTR + g4 * 8];
            short8 B1 = *(const short8*)&bcol[rp][e * BSTR + 32 + g4 * 8];

            if (!w6) {
                // 4 INDEPENDENT MFMAs (split accumulators)
                floatx4 aa = __builtin_amdgcn_mfma_f32_16x16x32_bf16(A0a, B0, bqa, 0, 0, 0);
                floatx4 a2 = __builtin_amdgcn_mfma_f32_16x16x32_bf16(A1a, B1, z4,  0, 0, 0);
                floatx4 ab = __builtin_amdgcn_mfma_f32_16x16x32_bf16(A0b, B0, bqb, 0, 0, 0);
                floatx4 b2 = __builtin_amdgcn_mfma_f32_16x16x32_bf16(A1b, B1, z4,  0, 0, 0);

                // vector combines -> v_pk_add_f32
                floatx4 sa = aa + a2;
                floatx4 sb = ab + b2;

                // scalar transcendentals (no packed trans exists)
                float EiA = __builtin_amdgcn_exp2f(sa[0]);
                float EiB = __builtin_amdgcn_exp2f(sb[0]);
                float EfA = __builtin_amdgcn_exp2f(sa[1]);
                float EfB = __builtin_amdgcn_exp2f(sb[1]);
                float EgA = __builtin_amdgcn_exp2f(sa[2]);
                float EgB = __builtin_amdgcn_exp2f(sb[2]);
                float EoA = __builtin_amdgcn_exp2f(sa[3]);
                float EoB = __builtin_amdgcn_exp2f(sb[3]);

                floatx2 Ei2 = {EiA, EiB};
                floatx2 Ef2 = {EfA, EfB};
                floatx2 Eg2 = {EgA, EgB};
                floatx2 Eo2 = {EoA, EoB};

                // merged-denominator cell update, PACKED (v_pk_fma/add/mul):
                //   P=(1+Ei)(1+Eg), F1=1+Ef
                //   c' = (c*P + K2N*(1-Eg)*F1) / (F1*P)
                floatx2 t2  = (Ei2 + Eg2) + 1.f;
                floatx2 P2  = __builtin_elementwise_fma(Ei2, Eg2, t2);
                floatx2 F12 = Ef2 + 1.f;
                floatx2 D2  = F12 * P2;
                floatx2 R2  = {__builtin_amdgcn_rcpf(D2[0]),
                               __builtin_amdgcn_rcpf(D2[1])};
                floatx2 T2  = (1.f - Eg2) * F12;
                cs2 = __builtin_elementwise_fma(cs2, P2, K2N * T2) * R2;

                floatx2 Ec2 = {__builtin_amdgcn_exp2f(cs2[0]),
                               __builtin_amdgcn_exp2f(cs2[1])};
                floatx2 u2  = (Eo2 + Ec2) + 1.f;
                floatx2 D3  = __builtin_elementwise_fma(Eo2, Ec2, u2);
                floatx2 Ro2 = {__builtin_amdgcn_rcpf(D3[0]),
                               __builtin_amdgcn_rcpf(D3[1])};
                floatx2 h2  = (1.f - Ec2) * Ro2;

                // pack two adjacent units into one aligned dword write
                unsigned hpk;
                asm("v_cvt_pk_bf16_f32 %0, %1, %2" : "=v"(hpk) : "v"(h2[0]), "v"(h2[1]));
                *(unsigned*)&bcol[wp][e * BSTR + ua] = hpk;
            } else {
                floatx4 acc = __builtin_amdgcn_mfma_f32_16x16x32_bf16(A0a, B0, bqa, 0, 0, 0);
                floatx4 ac2 = __builtin_amdgcn_mfma_f32_16x16x32_bf16(A1a, B1, z4,  0, 0, 0);

                float s0 = acc[0] + ac2[0];
                float Ei = __builtin_amdgcn_exp2f(s0);
                float Ef = __builtin_amdgcn_exp2f(acc[1] + ac2[1]);
                float Eg = __builtin_amdgcn_exp2f(acc[2] + ac2[2]);
                float Eo = __builtin_amdgcn_exp2f(acc[3] + ac2[3]);
                float P  = fmaf(Ei, Eg, (Ei + Eg) + 1.f);
                float F1 = 1.f + Ef;
                float R  = __builtin_amdgcn_rcpf(F1 * P);
                cs6 = fmaf(cs6, P, K2N * ((1.f - Eg) * F1)) * R;
                float Ec  = __builtin_amdgcn_exp2f(cs6);
                float Roc = __builtin_amdgcn_rcpf(fmaf(Eo, Ec, (Eo + Ec) + 1.f));
                float h   = (1.f - Ec) * Roc;

                bcol[wp][e * BSTR + wrow6] = __float2bfloat16((uB6 < HID) ? h : 0.f);
                if (yln) y_lds[tt * XST + e] = s0 + bfc;   // y[t-1], free
                if (xsv) bcol[wp][e * BSTR + 51] =
                             __float2bfloat16(x_lds[(tt + 1) * XST + e]);
            }

            __syncthreads();   // the ONE barrier per step
        }

        // flush y[t0-1 .. t0+CH-2] (slot tt <-> t0+tt-1); skip t = -1
        for (int i2 = tid; i2 < CH * EPB; i2 += NTH) {
            int ee = i2 / CH, tt = i2 % CH;
            int t = t0 + tt - 1;
            if (t >= 0)
                out[(size_t)(e0 + ee) * SEQT + t] = y_lds[tt * XST + ee];
        }
        // commit prefetched x for the next chunk
#pragma unroll
        for (int q = 0; q < 4; ++q) {
            int i2 = tid + q * NTH;
            int ee = i2 / (CH + 1), tt = i2 - ee * (CH + 1);
            x_lds[tt * XST + ee] = xpre[q];
        }
        __syncthreads();
    }

    // epilogue: y[998] from one extra MFMA pass over h_998 (in bcol[1])
    if (w6) {
        short8 B0 = *(const short8*)&bcol[1][e * BSTR + g4 * 8];
        short8 B1 = *(const short8*)&bcol[1][e * BSTR + 32 + g4 * 8];
        floatx4 acc = __builtin_amdgcn_mfma_f32_16x16x32_bf16(A0a, B0, bqa, 0, 0, 0);
        acc = __builtin_amdgcn_mfma_f32_16x16x32_bf16(A1a, B1, acc, 0, 0, 0);
        if (g4 == 3)
            out[(size_t)(e0 + e) * SEQT + (SEQT - 1)] = acc[0] + bfc;
    }
}

extern "C" void kernel_launch(void* const* d_in, const int* in_sizes, int n_in,
                              void* d_out, int out_size, void* d_ws, size_t ws_size,
                              hipStream_t stream) {
    const float* x    = (const float*)d_in[0];
    const float* W_ih = (const float*)d_in[1];
    const float* W_hh = (const float*)d_in[2];
    const float* b_ih = (const float*)d_in[3];
    const float* b_hh = (const float*)d_in[4];
    const float* W_fc = (const float*)d_in[5];
    const float* b_fc = (const float*)d_in[6];
    float* out = (float*)d_out;

    __hip_bfloat16* A_ext = (__hip_bfloat16*)d_ws;   // 208*64*2 = 26.6 KB

    prep_kernel<<<(MR * 64 + 255) / 256, 256, 0, stream>>>(W_hh, W_ih, W_fc, A_ext);
    lstm_mfma_kernel<<<4096 / EPB, NTH, 0, stream>>>(x, b_ih, b_hh,
                                                     b_fc, A_ext, out);
}